// Round 13
// baseline (134.875 us; speedup 1.0000x reference)
//
#include <hip/hip_runtime.h>
#include <hip/hip_bf16.h>

// NonlocalBlock: B=4, C=64, H=W=96 (N=9216), Ci=32, COMPRESSION=2 (M=4608).
// R18: the one untested occupancy cell. R17 (124.8, best) decomposes as
//      attn 52.3 + proj ~5-10 + ~55-60us harness reset dispatches (fixed).
//      R8->R9 proved occupancy helps 4->12 waves/CU; R12's 24-wave point was
//      spill-contaminated; 18 waves/CU on the PROVEN loop was never tested.
//      (a) attn: 6 waves/block (384 thr, TPW=24, rt=3), grid 768 unchanged ->
//          18 waves/CU at bounds(384,5) (102-reg cap vs ~75 used, no spill
//          possible); LDS union 45.8KB -> 3-block cap holds. Loop verbatim.
//      (b) proj: prefetch both n-tiles' x fragments before compute (latency
//          hiding at proj's 4.5 waves/CU).
//      Gates: WRITE_SIZE == 9216 KB exactly, VGPR <= 102, absmax 0.117.

#define NQ 9216
#define MM 4608
#define TPW 24         // 32-m tiles per wave (MM / 6 waves / 32)
#define LOG2E 1.44269504088896340736f

typedef __attribute__((ext_vector_type(8))) short bf16x8;   // 8 bf16, 4 VGPRs
typedef __attribute__((ext_vector_type(4))) float f32x4;    // MFMA C/D
typedef __attribute__((ext_vector_type(4))) unsigned short u16x4;

static __device__ __forceinline__ unsigned pk2(float a, float b) {
    __hip_bfloat162 h = __float22bfloat162_rn(make_float2(a, b));
    return *reinterpret_cast<unsigned*>(&h);   // low16=a, high16=b
}

// ---------------------------------------------------------------------------
// Kernel 1: projections. 576 blocks x 128 thr (2 waves, 32 n per wave via two
// sequential 16-n tiles reusing the weight fragments; both tiles' x fragments
// prefetched upfront). theta pre-scaled by LOG2E; phi [m][ci]; gT [ci][m].
// ---------------------------------------------------------------------------
__global__ __launch_bounds__(128, 4) void proj_kernel(
    const float* __restrict__ x,
    const float* __restrict__ wt, const float* __restrict__ bt,
    const float* __restrict__ wp, const float* __restrict__ bp,
    const float* __restrict__ wg, const float* __restrict__ bg,
    unsigned short* __restrict__ theta, unsigned short* __restrict__ phi,
    unsigned short* __restrict__ gT)
{
    __shared__ unsigned short gst[32 * 36];   // [ci 32][m-local 32 +4]

    const int tid  = threadIdx.x;
    const int wid  = tid >> 6;
    const int lane = tid & 63;
    const int q = lane >> 4;
    const int c = lane & 15;

    const int b   = blockIdx.x / 144;
    const int rem = blockIdx.x % 144;
    const int n0  = rem * 64 + wid * 32;     // this wave's 32 n-columns

    const float* Wm[3] = {wt, wp, wg};
    const float* Bm[3] = {bt, bp, bg};

    // weight fragments + bias: loaded ONCE, reused for both n-tiles
    bf16x8 wf[3][2][2];
    float bias[3][2];
#pragma unroll
    for (int p = 0; p < 3; ++p) {
#pragma unroll
        for (int ct = 0; ct < 2; ++ct) {
            bias[p][ct] = Bm[p][ct * 16 + c];
#pragma unroll
            for (int ks = 0; ks < 2; ++ks) {
                const float* wsrc = Wm[p] + (ct * 16 + c) * 64 + ks * 32 + q * 8;
                f32x4 w0 = *(const f32x4*)wsrc;
                f32x4 w1 = *(const f32x4*)(wsrc + 4);
                unsigned* wk = (unsigned*)&wf[p][ct][ks];
                wk[0] = pk2(w0[0], w0[1]); wk[1] = pk2(w0[2], w0[3]);
                wk[2] = pk2(w1[0], w1[1]); wk[3] = pk2(w1[2], w1[3]);
            }
        }
    }

    // prefetch BOTH tiles' x fragments (32 independent loads issued together)
    bf16x8 af[2][2];   // [n-tile][ks]
#pragma unroll
    for (int nt = 0; nt < 2; ++nt) {
        const int n0t = n0 + nt * 16;
#pragma unroll
        for (int ks = 0; ks < 2; ++ks) {
            unsigned* ap = (unsigned*)&af[nt][ks];
#pragma unroll
            for (int j2 = 0; j2 < 4; ++j2) {
                float x0 = x[(b * 64 + ks * 32 + q * 8 + j2 * 2) * NQ + n0t + c];
                float x1 = x[(b * 64 + ks * 32 + q * 8 + j2 * 2 + 1) * NQ + n0t + c];
                ap[j2] = pk2(x0, x1);
            }
        }
    }

#pragma unroll
    for (int nt = 0; nt < 2; ++nt) {
        const int n0t = n0 + nt * 16;
#pragma unroll
        for (int p = 0; p < 3; ++p) {
#pragma unroll
            for (int ct = 0; ct < 2; ++ct) {
                f32x4 acc = {0.f, 0.f, 0.f, 0.f};
                acc = __builtin_amdgcn_mfma_f32_16x16x32_bf16(af[nt][0], wf[p][ct][0], acc, 0, 0, 0);
                acc = __builtin_amdgcn_mfma_f32_16x16x32_bf16(af[nt][1], wf[p][ct][1], acc, 0, 0, 0);
#pragma unroll
                for (int r = 0; r < 4; ++r) acc[r] += bias[p][ct];
                const int ci = ct * 16 + c;
                if (p == 0) {
                    unsigned pv0 = pk2(acc[0] * LOG2E, acc[1] * LOG2E);
                    unsigned pv1 = pk2(acc[2] * LOG2E, acc[3] * LOG2E);
                    theta[(b * NQ + n0t + 4 * q + 0) * 32 + ci] = (unsigned short)pv0;
                    theta[(b * NQ + n0t + 4 * q + 1) * 32 + ci] = (unsigned short)(pv0 >> 16);
                    theta[(b * NQ + n0t + 4 * q + 2) * 32 + ci] = (unsigned short)pv1;
                    theta[(b * NQ + n0t + 4 * q + 3) * 32 + ci] = (unsigned short)(pv1 >> 16);
                } else {
                    unsigned pv = pk2(fmaxf(acc[0], acc[1]), fmaxf(acc[2], acc[3]));
                    if (p == 1) {
                        const int m0 = (n0t >> 1) + 2 * q;
                        phi[(b * MM + m0) * 32 + ci]     = (unsigned short)pv;
                        phi[(b * MM + m0 + 1) * 32 + ci] = (unsigned short)(pv >> 16);
                    } else {
                        // m-local (block) = wid*16 + nt*8 + 2q + {0,1}
                        *(unsigned int*)(gst + ci * 36 + wid * 16 + nt * 8 + 2 * q) = pv;
                    }
                }
            }
        }
    }

    __syncthreads();
    {   // coalesced gT store: 32 m x 32 ci (8 shorts per thread)
        const int ci = tid >> 2;
        const int m8 = (tid & 3) * 8;
        u16x4 v0 = *(const u16x4*)(gst + ci * 36 + m8);
        u16x4 v1 = *(const u16x4*)(gst + ci * 36 + m8 + 4);
        unsigned short* dst = gT + (size_t)(b * 32 + ci) * MM + rem * 32 + m8;
        *(u16x4*)dst       = v0;
        *(u16x4*)(dst + 4) = v1;
    }
}

// ---------------------------------------------------------------------------
// Kernel 2: attention + fused out-projection. Block = 6 waves m-splitting MM
// (768 m each) for one 48-q-row tile (rt=3). Per wave: R17's proven flash
// loop (single kf/vf, ones-row-MFMA lsum, WAR-safe single P buffer, 16B XOR
// swizzle) over TPW=24 tiles. Epilogue: overlay barrier; 6 f32 slices ->
// union LDS; reduce + normalize -> yld bf16; waves 0-3 out-project 16 chn
// each with bias + residual. Grid: 768 blocks x 384 thr (3 blocks/CU,
// 18 waves/CU). bounds(384,5): 102-reg cap.
// ---------------------------------------------------------------------------
__global__ __launch_bounds__(384, 5) void attn_kernel(
    const unsigned short* __restrict__ theta, const unsigned short* __restrict__ phi,
    const unsigned short* __restrict__ gT,
    const float* __restrict__ w_out, const float* __restrict__ b_out,
    const float* __restrict__ x, float* __restrict__ out)
{
    // Overlay: pld live during the flash loop; ep.* live only after the
    // post-loop barrier. max(18432, 45824) = 45824 B -> 3 blocks/CU cap.
    __shared__ union SharedU {
        unsigned short pld[6][48 * 32];          // per-wave P^T [n 48][m 32], 3KB each
        struct {
            float red[6][48][36];                // per-wave acc [n][ci 32 +4pad]
            float lred[6][48];                   // per-wave lsum per n
            unsigned short yld[32][50];          // normalized y^T [ci][n 48+2]
        } ep;
    } sh;

    const int tid  = threadIdx.x;
    const int w    = tid >> 6;
    const int lane = tid & 63;
    const int q  = lane >> 4;
    const int c  = lane & 15;
    const int sw = ((c >> 1) & 3) << 3;   // XOR swizzle on the m short-index (16B chunks)

    const int b  = blockIdx.x / 192;
    const int nb = (blockIdx.x % 192) * 48;      // block's 48 q-rows (all 6 waves)

    // Q B-frags: theta[n][ch], lane col n = c (per rt tile), k = q*8+j
    bf16x8 qf[3];
#pragma unroll
    for (int rt = 0; rt < 3; ++rt)
        qf[rt] = *(const bf16x8*)(theta + (b * NQ + nb + rt * 16 + c) * 32 + q * 8);

    // ones A-frag: row m=0 all-ones -> lanes with c==0 hold 1.0 in all k
    bf16x8 onef;
    {
        unsigned v = (c == 0) ? 0x3F803F80u : 0u;
        unsigned* op = (unsigned*)&onef;
        op[0] = v; op[1] = v; op[2] = v; op[3] = v;
    }

    const unsigned short* phiB = phi + (size_t)b * MM * 32;
    const unsigned short* gTB  = gT + (size_t)b * 32 * MM;
    unsigned short* myp = sh.pld[w];

    f32x4 acc[3][2];    // [rt n-tile][s2 ci-tile]: col=n, row=ci
    f32x4 lacc[3];      // D row0 (lanes q=0, reg0) = lsum per col n
#pragma unroll
    for (int rt = 0; rt < 3; ++rt) {
        lacc[rt] = (f32x4){0.f, 0.f, 0.f, 0.f};
#pragma unroll
        for (int s2 = 0; s2 < 2; ++s2) acc[rt][s2] = (f32x4){0.f, 0.f, 0.f, 0.f};
    }

    const int t0 = w * TPW;    // this wave's first 32-m tile
    bf16x8 kf[2], vf[2];

#define LOAD_KF(m0) do {                                                      \
    kf[0] = *(const bf16x8*)(phiB + ((m0) + c) * 32 + q * 8);                 \
    kf[1] = *(const bf16x8*)(phiB + ((m0) + 16 + c) * 32 + q * 8);            \
} while (0)

#define LOAD_VF(m0) do {                                                      \
    vf[0] = *(const bf16x8*)(gTB + c * MM + (m0) + q * 8);                    \
    vf[1] = *(const bf16x8*)(gTB + (16 + c) * MM + (m0) + q * 8);             \
} while (0)

// S(rt): 2 S-MFMAs + 8 exp2 + 4 cvt_pk + 2 ds_write_b64 (no lsum VALU adds)
#define S_STEP(rt) do {                                                      \
    _Pragma("unroll")                                                        \
    for (int mct = 0; mct < 2; ++mct) {                                      \
        f32x4 z = {0.f, 0.f, 0.f, 0.f};                                      \
        f32x4 s = __builtin_amdgcn_mfma_f32_16x16x32_bf16(kf[mct], qf[rt], z, 0, 0, 0); \
        uint2 hv = {pk2(__builtin_amdgcn_exp2f(s[0]), __builtin_amdgcn_exp2f(s[1])),    \
                    pk2(__builtin_amdgcn_exp2f(s[2]), __builtin_amdgcn_exp2f(s[3]))};   \
        *(uint2*)(myp + (((rt) * 16 + c) << 5) + ((mct * 16 + 4 * q) ^ sw)) = hv;       \
    }                                                                        \
} while (0)

// PV(rt): 1 ds_read_b128 + 2 acc-MFMAs + 1 lsum-MFMA (ones row)
#define PV_STEP(rt) do {                                                     \
    bf16x8 pf = *(const bf16x8*)(myp + (((rt) * 16 + c) << 5) + ((q * 8) ^ sw)); \
    acc[rt][0] = __builtin_amdgcn_mfma_f32_16x16x32_bf16(vf[0], pf, acc[rt][0], 0, 0, 0); \
    acc[rt][1] = __builtin_amdgcn_mfma_f32_16x16x32_bf16(vf[1], pf, acc[rt][1], 0, 0, 0); \
    lacc[rt]   = __builtin_amdgcn_mfma_f32_16x16x32_bf16(onef,  pf, lacc[rt],   0, 0, 0); \
} while (0)

    // ---- prologue: tile 0 S/exp/write ----
    LOAD_KF(t0 * 32);
    LOAD_VF(t0 * 32);
    S_STEP(0); S_STEP(1); S_STEP(2);

    // ---- steady state (R13/R17-proven schedule) ----
    for (int mi = 1; mi < TPW; ++mi) {
        const int m0 = (t0 + mi) * 32;
        LOAD_KF(m0);                          // kf(i), consumed by S(i) below
        PV_STEP(0); PV_STEP(1); PV_STEP(2);   // P(i-1) x vf(i-1)
        LOAD_VF(m0);                          // vf(i), consumed next iter
        S_STEP(0); S_STEP(1); S_STEP(2);
    }

    // ---- epilogue: PV of last tile ----
    PV_STEP(0); PV_STEP(1); PV_STEP(2);

#undef LOAD_KF
#undef LOAD_VF
#undef S_STEP
#undef PV_STEP

    // ---- overlay safety: all pld reads done before ep.* writes ----
    __syncthreads();

    // ---- stage per-wave partial slices ----
    // lacc D row0 lives in lanes q=0 (lane<16), reg 0
    if (lane < 16) {
        sh.ep.lred[w][lane]      = lacc[0][0];
        sh.ep.lred[w][16 + lane] = lacc[1][0];
        sh.ep.lred[w][32 + lane] = lacc[2][0];
    }
#pragma unroll
    for (int rt = 0; rt < 3; ++rt)
#pragma unroll
        for (int s2 = 0; s2 < 2; ++s2)
            *(f32x4*)&sh.ep.red[w][rt * 16 + c][s2 * 16 + 4 * q] = acc[rt][s2];

    __syncthreads();

    // ---- cross-wave sum + normalize -> yld bf16 [ci][n] ----
    if (tid < 192) {
        const int n   = tid % 48;            // 48 n
        const int cig = (tid / 48) * 8;      // 8 ci values per thread
        float ls = ((sh.ep.lred[0][n] + sh.ep.lred[1][n]) +
                    (sh.ep.lred[2][n] + sh.ep.lred[3][n])) +
                   (sh.ep.lred[4][n] + sh.ep.lred[5][n]);
        float inv = 1.0f / ls;
        f32x4 s0 = {0.f, 0.f, 0.f, 0.f}, s1 = {0.f, 0.f, 0.f, 0.f};
#pragma unroll
        for (int ww = 0; ww < 6; ++ww) {
            s0 += *(const f32x4*)&sh.ep.red[ww][n][cig];
            s1 += *(const f32x4*)&sh.ep.red[ww][n][cig + 4];
        }
#pragma unroll
        for (int k = 0; k < 4; ++k) {
            sh.ep.yld[cig + k][n]     = (unsigned short)(pk2(s0[k] * inv, 0.f) & 0xffff);
            sh.ep.yld[cig + 4 + k][n] = (unsigned short)(pk2(s1[k] * inv, 0.f) & 0xffff);
        }
    }
    __syncthreads();

    // ---- fused out-projection: waves 0-3 -> chn rows w*16..w*16+15 ----
    if (w < 4) {
        bf16x8 wof;
        {
            const float* wsrc = w_out + (w * 16 + c) * 32 + q * 8;
            f32x4 w0 = *(const f32x4*)wsrc;
            f32x4 w1 = *(const f32x4*)(wsrc + 4);
            unsigned* wk = (unsigned*)&wof;
            wk[0] = pk2(w0[0], w0[1]); wk[1] = pk2(w0[2], w0[3]);
            wk[2] = pk2(w1[0], w1[1]); wk[3] = pk2(w1[2], w1[3]);
        }
#pragma unroll
        for (int nt = 0; nt < 3; ++nt) {
            bf16x8 yf;
            unsigned short* yp = (unsigned short*)&yf;
#pragma unroll
            for (int j = 0; j < 8; ++j)
                yp[j] = sh.ep.yld[q * 8 + j][nt * 16 + c];
            f32x4 z = {0.f, 0.f, 0.f, 0.f};
            f32x4 o = __builtin_amdgcn_mfma_f32_16x16x32_bf16(wof, yf, z, 0, 0, 0);
#pragma unroll
            for (int r = 0; r < 4; ++r) {
                const int chn = w * 16 + 4 * q + r;
                const size_t addr = (size_t)(b * 64 + chn) * NQ + nb + nt * 16 + c;
                out[addr] = o[r] + b_out[chn] + x[addr];
            }
        }
    }
}

extern "C" void kernel_launch(void* const* d_in, const int* in_sizes, int n_in,
                              void* d_out, int out_size, void* d_ws, size_t ws_size,
                              hipStream_t stream) {
    const float* x       = (const float*)d_in[0];
    const float* w_theta = (const float*)d_in[1];
    const float* b_theta = (const float*)d_in[2];
    const float* w_phi   = (const float*)d_in[3];
    const float* b_phi   = (const float*)d_in[4];
    const float* w_g     = (const float*)d_in[5];
    const float* b_g     = (const float*)d_in[6];
    const float* w_out   = (const float*)d_in[7];
    const float* b_out   = (const float*)d_in[8];
    float* out = (float*)d_out;

    // ws layout (bytes):
    //   theta bf16 [4][9216][32] : 2,359,296
    //   phi   bf16 [4][4608][32] : 1,179,648
    //   gT    bf16 [4][32][4608] : 1,179,648
    unsigned short* theta = (unsigned short*)d_ws;
    unsigned short* phi   = theta + 4 * NQ * 32;
    unsigned short* gT    = phi + 4 * MM * 32;

    proj_kernel<<<576, 128, 0, stream>>>(x, w_theta, b_theta, w_phi, b_phi,
                                         w_g, b_g, theta, phi, gT);
    attn_kernel<<<768, 384, 0, stream>>>(theta, phi, gT, w_out, b_out, x, out);
}

// Round 14
// 131.997 us; speedup vs baseline: 1.0218x; 1.0218x over previous
//
#include <hip/hip_runtime.h>
#include <hip/hip_bf16.h>

// NonlocalBlock: B=4, C=64, H=W=96 (N=9216), Ci=32, COMPRESSION=2 (M=4608).
// R19: R18's 6-wave occupancy test, decontaminated. R18 spilled because the
//      VGPR_Count counter EXCLUDES AGPRs (unified file): R17's true footprint
//      is ~56 VGPR + ~36 AGPR = ~92, and bounds(384,5)'s 102-reg cap left no
//      slack -> allocator squeezed to 48 arch regs + 13.5MB scratch. Fix:
//      bounds(384,4) = 128-reg cap (92 + 35 slack). LDS 45.8KB then binds at
//      3 blocks/CU = 18 waves/CU = 4.5/SIMD -- the clean 1.5x wave-density
//      test vs R17's 12/CU. Loop and epilogue byte-identical to R18.
//      Gates: WRITE == 9216 KB exactly, FETCH ~16.6MB, VGPR >= 56.
//      Pre-commit: win -> keep; neutral/loss -> R17 is this structure's floor.

#define NQ 9216
#define MM 4608
#define TPW 24         // 32-m tiles per wave (MM / 6 waves / 32)
#define LOG2E 1.44269504088896340736f

typedef __attribute__((ext_vector_type(8))) short bf16x8;   // 8 bf16, 4 VGPRs
typedef __attribute__((ext_vector_type(4))) float f32x4;    // MFMA C/D
typedef __attribute__((ext_vector_type(4))) unsigned short u16x4;

static __device__ __forceinline__ unsigned pk2(float a, float b) {
    __hip_bfloat162 h = __float22bfloat162_rn(make_float2(a, b));
    return *reinterpret_cast<unsigned*>(&h);   // low16=a, high16=b
}

// ---------------------------------------------------------------------------
// Kernel 1: projections. 576 blocks x 128 thr (2 waves, 32 n per wave via two
// sequential 16-n tiles reusing the weight fragments; both tiles' x fragments
// prefetched upfront). theta pre-scaled by LOG2E; phi [m][ci]; gT [ci][m].
// ---------------------------------------------------------------------------
__global__ __launch_bounds__(128, 4) void proj_kernel(
    const float* __restrict__ x,
    const float* __restrict__ wt, const float* __restrict__ bt,
    const float* __restrict__ wp, const float* __restrict__ bp,
    const float* __restrict__ wg, const float* __restrict__ bg,
    unsigned short* __restrict__ theta, unsigned short* __restrict__ phi,
    unsigned short* __restrict__ gT)
{
    __shared__ unsigned short gst[32 * 36];   // [ci 32][m-local 32 +4]

    const int tid  = threadIdx.x;
    const int wid  = tid >> 6;
    const int lane = tid & 63;
    const int q = lane >> 4;
    const int c = lane & 15;

    const int b   = blockIdx.x / 144;
    const int rem = blockIdx.x % 144;
    const int n0  = rem * 64 + wid * 32;     // this wave's 32 n-columns

    const float* Wm[3] = {wt, wp, wg};
    const float* Bm[3] = {bt, bp, bg};

    // weight fragments + bias: loaded ONCE, reused for both n-tiles
    bf16x8 wf[3][2][2];
    float bias[3][2];
#pragma unroll
    for (int p = 0; p < 3; ++p) {
#pragma unroll
        for (int ct = 0; ct < 2; ++ct) {
            bias[p][ct] = Bm[p][ct * 16 + c];
#pragma unroll
            for (int ks = 0; ks < 2; ++ks) {
                const float* wsrc = Wm[p] + (ct * 16 + c) * 64 + ks * 32 + q * 8;
                f32x4 w0 = *(const f32x4*)wsrc;
                f32x4 w1 = *(const f32x4*)(wsrc + 4);
                unsigned* wk = (unsigned*)&wf[p][ct][ks];
                wk[0] = pk2(w0[0], w0[1]); wk[1] = pk2(w0[2], w0[3]);
                wk[2] = pk2(w1[0], w1[1]); wk[3] = pk2(w1[2], w1[3]);
            }
        }
    }

    // prefetch BOTH tiles' x fragments (32 independent loads issued together)
    bf16x8 af[2][2];   // [n-tile][ks]
#pragma unroll
    for (int nt = 0; nt < 2; ++nt) {
        const int n0t = n0 + nt * 16;
#pragma unroll
        for (int ks = 0; ks < 2; ++ks) {
            unsigned* ap = (unsigned*)&af[nt][ks];
#pragma unroll
            for (int j2 = 0; j2 < 4; ++j2) {
                float x0 = x[(b * 64 + ks * 32 + q * 8 + j2 * 2) * NQ + n0t + c];
                float x1 = x[(b * 64 + ks * 32 + q * 8 + j2 * 2 + 1) * NQ + n0t + c];
                ap[j2] = pk2(x0, x1);
            }
        }
    }

#pragma unroll
    for (int nt = 0; nt < 2; ++nt) {
        const int n0t = n0 + nt * 16;
#pragma unroll
        for (int p = 0; p < 3; ++p) {
#pragma unroll
            for (int ct = 0; ct < 2; ++ct) {
                f32x4 acc = {0.f, 0.f, 0.f, 0.f};
                acc = __builtin_amdgcn_mfma_f32_16x16x32_bf16(af[nt][0], wf[p][ct][0], acc, 0, 0, 0);
                acc = __builtin_amdgcn_mfma_f32_16x16x32_bf16(af[nt][1], wf[p][ct][1], acc, 0, 0, 0);
#pragma unroll
                for (int r = 0; r < 4; ++r) acc[r] += bias[p][ct];
                const int ci = ct * 16 + c;
                if (p == 0) {
                    unsigned pv0 = pk2(acc[0] * LOG2E, acc[1] * LOG2E);
                    unsigned pv1 = pk2(acc[2] * LOG2E, acc[3] * LOG2E);
                    theta[(b * NQ + n0t + 4 * q + 0) * 32 + ci] = (unsigned short)pv0;
                    theta[(b * NQ + n0t + 4 * q + 1) * 32 + ci] = (unsigned short)(pv0 >> 16);
                    theta[(b * NQ + n0t + 4 * q + 2) * 32 + ci] = (unsigned short)pv1;
                    theta[(b * NQ + n0t + 4 * q + 3) * 32 + ci] = (unsigned short)(pv1 >> 16);
                } else {
                    unsigned pv = pk2(fmaxf(acc[0], acc[1]), fmaxf(acc[2], acc[3]));
                    if (p == 1) {
                        const int m0 = (n0t >> 1) + 2 * q;
                        phi[(b * MM + m0) * 32 + ci]     = (unsigned short)pv;
                        phi[(b * MM + m0 + 1) * 32 + ci] = (unsigned short)(pv >> 16);
                    } else {
                        // m-local (block) = wid*16 + nt*8 + 2q + {0,1}
                        *(unsigned int*)(gst + ci * 36 + wid * 16 + nt * 8 + 2 * q) = pv;
                    }
                }
            }
        }
    }

    __syncthreads();
    {   // coalesced gT store: 32 m x 32 ci (8 shorts per thread)
        const int ci = tid >> 2;
        const int m8 = (tid & 3) * 8;
        u16x4 v0 = *(const u16x4*)(gst + ci * 36 + m8);
        u16x4 v1 = *(const u16x4*)(gst + ci * 36 + m8 + 4);
        unsigned short* dst = gT + (size_t)(b * 32 + ci) * MM + rem * 32 + m8;
        *(u16x4*)dst       = v0;
        *(u16x4*)(dst + 4) = v1;
    }
}

// ---------------------------------------------------------------------------
// Kernel 2: attention + fused out-projection. Block = 6 waves m-splitting MM
// (768 m each) for one 48-q-row tile (rt=3). Per wave: R17's proven flash
// loop (single kf/vf, ones-row-MFMA lsum, WAR-safe single P buffer, 16B XOR
// swizzle) over TPW=24 tiles. Epilogue: overlay barrier; 6 f32 slices ->
// union LDS; reduce + normalize -> yld bf16; waves 0-3 out-project 16 chn
// each with bias + residual. Grid: 768 blocks x 384 thr. bounds(384,4):
// 128-reg cap (true footprint ~92 incl. AGPRs); LDS 45.8KB binds occupancy
// at 3 blocks/CU = 18 waves/CU.
// ---------------------------------------------------------------------------
__global__ __launch_bounds__(384, 4) void attn_kernel(
    const unsigned short* __restrict__ theta, const unsigned short* __restrict__ phi,
    const unsigned short* __restrict__ gT,
    const float* __restrict__ w_out, const float* __restrict__ b_out,
    const float* __restrict__ x, float* __restrict__ out)
{
    // Overlay: pld live during the flash loop; ep.* live only after the
    // post-loop barrier. max(18432, 45824) = 45824 B -> 3 blocks/CU cap.
    __shared__ union SharedU {
        unsigned short pld[6][48 * 32];          // per-wave P^T [n 48][m 32], 3KB each
        struct {
            float red[6][48][36];                // per-wave acc [n][ci 32 +4pad]
            float lred[6][48];                   // per-wave lsum per n
            unsigned short yld[32][50];          // normalized y^T [ci][n 48+2]
        } ep;
    } sh;

    const int tid  = threadIdx.x;
    const int w    = tid >> 6;
    const int lane = tid & 63;
    const int q  = lane >> 4;
    const int c  = lane & 15;
    const int sw = ((c >> 1) & 3) << 3;   // XOR swizzle on the m short-index (16B chunks)

    const int b  = blockIdx.x / 192;
    const int nb = (blockIdx.x % 192) * 48;      // block's 48 q-rows (all 6 waves)

    // Q B-frags: theta[n][ch], lane col n = c (per rt tile), k = q*8+j
    bf16x8 qf[3];
#pragma unroll
    for (int rt = 0; rt < 3; ++rt)
        qf[rt] = *(const bf16x8*)(theta + (b * NQ + nb + rt * 16 + c) * 32 + q * 8);

    // ones A-frag: row m=0 all-ones -> lanes with c==0 hold 1.0 in all k
    bf16x8 onef;
    {
        unsigned v = (c == 0) ? 0x3F803F80u : 0u;
        unsigned* op = (unsigned*)&onef;
        op[0] = v; op[1] = v; op[2] = v; op[3] = v;
    }

    const unsigned short* phiB = phi + (size_t)b * MM * 32;
    const unsigned short* gTB  = gT + (size_t)b * 32 * MM;
    unsigned short* myp = sh.pld[w];

    f32x4 acc[3][2];    // [rt n-tile][s2 ci-tile]: col=n, row=ci
    f32x4 lacc[3];      // D row0 (lanes q=0, reg0) = lsum per col n
#pragma unroll
    for (int rt = 0; rt < 3; ++rt) {
        lacc[rt] = (f32x4){0.f, 0.f, 0.f, 0.f};
#pragma unroll
        for (int s2 = 0; s2 < 2; ++s2) acc[rt][s2] = (f32x4){0.f, 0.f, 0.f, 0.f};
    }

    const int t0 = w * TPW;    // this wave's first 32-m tile
    bf16x8 kf[2], vf[2];

#define LOAD_KF(m0) do {                                                      \
    kf[0] = *(const bf16x8*)(phiB + ((m0) + c) * 32 + q * 8);                 \
    kf[1] = *(const bf16x8*)(phiB + ((m0) + 16 + c) * 32 + q * 8);            \
} while (0)

#define LOAD_VF(m0) do {                                                      \
    vf[0] = *(const bf16x8*)(gTB + c * MM + (m0) + q * 8);                    \
    vf[1] = *(const bf16x8*)(gTB + (16 + c) * MM + (m0) + q * 8);             \
} while (0)

// S(rt): 2 S-MFMAs + 8 exp2 + 4 cvt_pk + 2 ds_write_b64 (no lsum VALU adds)
#define S_STEP(rt) do {                                                      \
    _Pragma("unroll")                                                        \
    for (int mct = 0; mct < 2; ++mct) {                                      \
        f32x4 z = {0.f, 0.f, 0.f, 0.f};                                      \
        f32x4 s = __builtin_amdgcn_mfma_f32_16x16x32_bf16(kf[mct], qf[rt], z, 0, 0, 0); \
        uint2 hv = {pk2(__builtin_amdgcn_exp2f(s[0]), __builtin_amdgcn_exp2f(s[1])),    \
                    pk2(__builtin_amdgcn_exp2f(s[2]), __builtin_amdgcn_exp2f(s[3]))};   \
        *(uint2*)(myp + (((rt) * 16 + c) << 5) + ((mct * 16 + 4 * q) ^ sw)) = hv;       \
    }                                                                        \
} while (0)

// PV(rt): 1 ds_read_b128 + 2 acc-MFMAs + 1 lsum-MFMA (ones row)
#define PV_STEP(rt) do {                                                     \
    bf16x8 pf = *(const bf16x8*)(myp + (((rt) * 16 + c) << 5) + ((q * 8) ^ sw)); \
    acc[rt][0] = __builtin_amdgcn_mfma_f32_16x16x32_bf16(vf[0], pf, acc[rt][0], 0, 0, 0); \
    acc[rt][1] = __builtin_amdgcn_mfma_f32_16x16x32_bf16(vf[1], pf, acc[rt][1], 0, 0, 0); \
    lacc[rt]   = __builtin_amdgcn_mfma_f32_16x16x32_bf16(onef,  pf, lacc[rt],   0, 0, 0); \
} while (0)

    // ---- prologue: tile 0 S/exp/write ----
    LOAD_KF(t0 * 32);
    LOAD_VF(t0 * 32);
    S_STEP(0); S_STEP(1); S_STEP(2);

    // ---- steady state (R13/R17-proven schedule) ----
    for (int mi = 1; mi < TPW; ++mi) {
        const int m0 = (t0 + mi) * 32;
        LOAD_KF(m0);                          // kf(i), consumed by S(i) below
        PV_STEP(0); PV_STEP(1); PV_STEP(2);   // P(i-1) x vf(i-1)
        LOAD_VF(m0);                          // vf(i), consumed next iter
        S_STEP(0); S_STEP(1); S_STEP(2);
    }

    // ---- epilogue: PV of last tile ----
    PV_STEP(0); PV_STEP(1); PV_STEP(2);

#undef LOAD_KF
#undef LOAD_VF
#undef S_STEP
#undef PV_STEP

    // ---- overlay safety: all pld reads done before ep.* writes ----
    __syncthreads();

    // ---- stage per-wave partial slices ----
    // lacc D row0 lives in lanes q=0 (lane<16), reg 0
    if (lane < 16) {
        sh.ep.lred[w][lane]      = lacc[0][0];
        sh.ep.lred[w][16 + lane] = lacc[1][0];
        sh.ep.lred[w][32 + lane] = lacc[2][0];
    }
#pragma unroll
    for (int rt = 0; rt < 3; ++rt)
#pragma unroll
        for (int s2 = 0; s2 < 2; ++s2)
            *(f32x4*)&sh.ep.red[w][rt * 16 + c][s2 * 16 + 4 * q] = acc[rt][s2];

    __syncthreads();

    // ---- cross-wave sum + normalize -> yld bf16 [ci][n] ----
    if (tid < 192) {
        const int n   = tid % 48;            // 48 n
        const int cig = (tid / 48) * 8;      // 8 ci values per thread
        float ls = ((sh.ep.lred[0][n] + sh.ep.lred[1][n]) +
                    (sh.ep.lred[2][n] + sh.ep.lred[3][n])) +
                   (sh.ep.lred[4][n] + sh.ep.lred[5][n]);
        float inv = 1.0f / ls;
        f32x4 s0 = {0.f, 0.f, 0.f, 0.f}, s1 = {0.f, 0.f, 0.f, 0.f};
#pragma unroll
        for (int ww = 0; ww < 6; ++ww) {
            s0 += *(const f32x4*)&sh.ep.red[ww][n][cig];
            s1 += *(const f32x4*)&sh.ep.red[ww][n][cig + 4];
        }
#pragma unroll
        for (int k = 0; k < 4; ++k) {
            sh.ep.yld[cig + k][n]     = (unsigned short)(pk2(s0[k] * inv, 0.f) & 0xffff);
            sh.ep.yld[cig + 4 + k][n] = (unsigned short)(pk2(s1[k] * inv, 0.f) & 0xffff);
        }
    }
    __syncthreads();

    // ---- fused out-projection: waves 0-3 -> chn rows w*16..w*16+15 ----
    if (w < 4) {
        bf16x8 wof;
        {
            const float* wsrc = w_out + (w * 16 + c) * 32 + q * 8;
            f32x4 w0 = *(const f32x4*)wsrc;
            f32x4 w1 = *(const f32x4*)(wsrc + 4);
            unsigned* wk = (unsigned*)&wof;
            wk[0] = pk2(w0[0], w0[1]); wk[1] = pk2(w0[2], w0[3]);
            wk[2] = pk2(w1[1 - 1], w1[1]); wk[3] = pk2(w1[2], w1[3]);
        }
#pragma unroll
        for (int nt = 0; nt < 3; ++nt) {
            bf16x8 yf;
            unsigned short* yp = (unsigned short*)&yf;
#pragma unroll
            for (int j = 0; j < 8; ++j)
                yp[j] = sh.ep.yld[q * 8 + j][nt * 16 + c];
            f32x4 z = {0.f, 0.f, 0.f, 0.f};
            f32x4 o = __builtin_amdgcn_mfma_f32_16x16x32_bf16(wof, yf, z, 0, 0, 0);
#pragma unroll
            for (int r = 0; r < 4; ++r) {
                const int chn = w * 16 + 4 * q + r;
                const size_t addr = (size_t)(b * 64 + chn) * NQ + nb + nt * 16 + c;
                out[addr] = o[r] + b_out[chn] + x[addr];
            }
        }
    }
}

extern "C" void kernel_launch(void* const* d_in, const int* in_sizes, int n_in,
                              void* d_out, int out_size, void* d_ws, size_t ws_size,
                              hipStream_t stream) {
    const float* x       = (const float*)d_in[0];
    const float* w_theta = (const float*)d_in[1];
    const float* b_theta = (const float*)d_in[2];
    const float* w_phi   = (const float*)d_in[3];
    const float* b_phi   = (const float*)d_in[4];
    const float* w_g     = (const float*)d_in[5];
    const float* b_g     = (const float*)d_in[6];
    const float* w_out   = (const float*)d_in[7];
    const float* b_out   = (const float*)d_in[8];
    float* out = (float*)d_out;

    // ws layout (bytes):
    //   theta bf16 [4][9216][32] : 2,359,296
    //   phi   bf16 [4][4608][32] : 1,179,648
    //   gT    bf16 [4][32][4608] : 1,179,648
    unsigned short* theta = (unsigned short*)d_ws;
    unsigned short* phi   = theta + 4 * NQ * 32;
    unsigned short* gT    = phi + 4 * MM * 32;

    proj_kernel<<<576, 128, 0, stream>>>(x, w_theta, b_theta, w_phi, b_phi,
                                         w_g, b_g, theta, phi, gT);
    attn_kernel<<<768, 384, 0, stream>>>(theta, phi, gT, w_out, b_out, x, out);
}

// Round 16
// 125.764 us; speedup vs baseline: 1.0724x; 1.0496x over previous
//
#include <hip/hip_runtime.h>
#include <hip/hip_bf16.h>

// NonlocalBlock: B=4, C=64, H=W=96 (N=9216), Ci=32, COMPRESSION=2 (M=4608).
// R20-resubmit (R15 attempt died on infra: "MI355X container failed twice";
//      kernel never ran). R17 base (124.8us best; occupancy axis closed by
//      R19's clean negative) + s_setprio(1)/(0) around the 9-MFMA PV cluster
//      (T5; the one zero-cost unfalsified lever). No register/LDS/structure
//      change vs R17. Structural constraint at this floor: attn 52us = ~28us
//      VALU/trans issue + ~10us MFMA + ~14us dependency padding on
//      S-MFMA->exp2->pack->LDS->PV; HBM 6%, MFMA 20% (not a HW roofline).
//      Falsified: interleave, occupancy up, KVBLK=64, kf-prefetch,
//      cooperative fusion. Gates: WRITE == 9216 KB, VGPR 56, absmax 0.117.

#define NQ 9216
#define MM 4608
#define TPW 36         // 32-m tiles per wave (MM / 4 waves / 32)
#define LOG2E 1.44269504088896340736f

typedef __attribute__((ext_vector_type(8))) short bf16x8;   // 8 bf16, 4 VGPRs
typedef __attribute__((ext_vector_type(4))) float f32x4;    // MFMA C/D
typedef __attribute__((ext_vector_type(4))) unsigned short u16x4;

static __device__ __forceinline__ unsigned pk2(float a, float b) {
    __hip_bfloat162 h = __float22bfloat162_rn(make_float2(a, b));
    return *reinterpret_cast<unsigned*>(&h);   // low16=a, high16=b
}

// ---------------------------------------------------------------------------
// Kernel 1: projections. 576 blocks x 128 thr (2 waves, 32 n per wave via two
// sequential 16-n tiles reusing the weight fragments). theta pre-scaled by
// LOG2E; phi [m][ci]; gT [ci][m] via LDS transpose (32-m block tile).
// (R17 verbatim.)
// ---------------------------------------------------------------------------
__global__ __launch_bounds__(128, 4) void proj_kernel(
    const float* __restrict__ x,
    const float* __restrict__ wt, const float* __restrict__ bt,
    const float* __restrict__ wp, const float* __restrict__ bp,
    const float* __restrict__ wg, const float* __restrict__ bg,
    unsigned short* __restrict__ theta, unsigned short* __restrict__ phi,
    unsigned short* __restrict__ gT)
{
    __shared__ unsigned short gst[32 * 36];   // [ci 32][m-local 32 +4]

    const int tid  = threadIdx.x;
    const int wid  = tid >> 6;
    const int lane = tid & 63;
    const int q = lane >> 4;
    const int c = lane & 15;

    const int b   = blockIdx.x / 144;
    const int rem = blockIdx.x % 144;
    const int n0  = rem * 64 + wid * 32;     // this wave's 32 n-columns

    const float* Wm[3] = {wt, wp, wg};
    const float* Bm[3] = {bt, bp, bg};

    // weight fragments + bias: loaded ONCE, reused for both n-tiles
    bf16x8 wf[3][2][2];
    float bias[3][2];
#pragma unroll
    for (int p = 0; p < 3; ++p) {
#pragma unroll
        for (int ct = 0; ct < 2; ++ct) {
            bias[p][ct] = Bm[p][ct * 16 + c];
#pragma unroll
            for (int ks = 0; ks < 2; ++ks) {
                const float* wsrc = Wm[p] + (ct * 16 + c) * 64 + ks * 32 + q * 8;
                f32x4 w0 = *(const f32x4*)wsrc;
                f32x4 w1 = *(const f32x4*)(wsrc + 4);
                unsigned* wk = (unsigned*)&wf[p][ct][ks];
                wk[0] = pk2(w0[0], w0[1]); wk[1] = pk2(w0[2], w0[3]);
                wk[2] = pk2(w1[0], w1[1]); wk[3] = pk2(w1[2], w1[3]);
            }
        }
    }

#pragma unroll
    for (int nt = 0; nt < 2; ++nt) {
        const int n0t = n0 + nt * 16;

        bf16x8 af[2];
#pragma unroll
        for (int ks = 0; ks < 2; ++ks) {
            unsigned* ap = (unsigned*)&af[ks];
#pragma unroll
            for (int j2 = 0; j2 < 4; ++j2) {
                float x0 = x[(b * 64 + ks * 32 + q * 8 + j2 * 2) * NQ + n0t + c];
                float x1 = x[(b * 64 + ks * 32 + q * 8 + j2 * 2 + 1) * NQ + n0t + c];
                ap[j2] = pk2(x0, x1);
            }
        }

#pragma unroll
        for (int p = 0; p < 3; ++p) {
#pragma unroll
            for (int ct = 0; ct < 2; ++ct) {
                f32x4 acc = {0.f, 0.f, 0.f, 0.f};
                acc = __builtin_amdgcn_mfma_f32_16x16x32_bf16(af[0], wf[p][ct][0], acc, 0, 0, 0);
                acc = __builtin_amdgcn_mfma_f32_16x16x32_bf16(af[1], wf[p][ct][1], acc, 0, 0, 0);
#pragma unroll
                for (int r = 0; r < 4; ++r) acc[r] += bias[p][ct];
                const int ci = ct * 16 + c;
                if (p == 0) {
                    unsigned pv0 = pk2(acc[0] * LOG2E, acc[1] * LOG2E);
                    unsigned pv1 = pk2(acc[2] * LOG2E, acc[3] * LOG2E);
                    theta[(b * NQ + n0t + 4 * q + 0) * 32 + ci] = (unsigned short)pv0;
                    theta[(b * NQ + n0t + 4 * q + 1) * 32 + ci] = (unsigned short)(pv0 >> 16);
                    theta[(b * NQ + n0t + 4 * q + 2) * 32 + ci] = (unsigned short)pv1;
                    theta[(b * NQ + n0t + 4 * q + 3) * 32 + ci] = (unsigned short)(pv1 >> 16);
                } else {
                    unsigned pv = pk2(fmaxf(acc[0], acc[1]), fmaxf(acc[2], acc[3]));
                    if (p == 1) {
                        const int m0 = (n0t >> 1) + 2 * q;
                        phi[(b * MM + m0) * 32 + ci]     = (unsigned short)pv;
                        phi[(b * MM + m0 + 1) * 32 + ci] = (unsigned short)(pv >> 16);
                    } else {
                        // m-local (block) = wid*16 + nt*8 + 2q + {0,1}
                        *(unsigned int*)(gst + ci * 36 + wid * 16 + nt * 8 + 2 * q) = pv;
                    }
                }
            }
        }
    }

    __syncthreads();
    {   // coalesced gT store: 32 m x 32 ci (8 shorts per thread)
        const int ci = tid >> 2;
        const int m8 = (tid & 3) * 8;
        u16x4 v0 = *(const u16x4*)(gst + ci * 36 + m8);
        u16x4 v1 = *(const u16x4*)(gst + ci * 36 + m8 + 4);
        unsigned short* dst = gT + (size_t)(b * 32 + ci) * MM + rem * 32 + m8;
        *(u16x4*)dst       = v0;
        *(u16x4*)(dst + 4) = v1;
    }
}

// ---------------------------------------------------------------------------
// Kernel 2: attention + fused out-projection. Block = 4 waves m-splitting MM
// (1152 m each) for one 48-q-row tile (rt=3). R17's flash loop (ones-row-MFMA
// lsum, single kf/vf, WAR-safe single P buffer, 16B XOR swizzle) with
// s_setprio(1)/(0) around the PV MFMA cluster (T5). Epilogue: overlay
// barrier; f32 slices -> union LDS; reduce + normalize -> yld bf16; fused
// out-projection with bias + residual. Grid: 768 blocks x 256 thr.
// ---------------------------------------------------------------------------
__global__ __launch_bounds__(256, 4) void attn_kernel(
    const unsigned short* __restrict__ theta, const unsigned short* __restrict__ phi,
    const unsigned short* __restrict__ gT,
    const float* __restrict__ w_out, const float* __restrict__ b_out,
    const float* __restrict__ x, float* __restrict__ out)
{
    // Overlay: pld live during the flash loop; ep.* live only after the
    // post-loop barrier. max(12288, 31616) = 31616 B.
    __shared__ union SharedU {
        unsigned short pld[4][48 * 32];          // per-wave P^T [n 48][m 32], 3KB each
        struct {
            float red[4][48][36];                // per-wave acc [n][ci 32 +4pad]
            float lred[4][48];                   // per-wave lsum per n
            unsigned short yld[32][50];          // normalized y^T [ci][n 48+2]
        } ep;
    } sh;

    const int tid  = threadIdx.x;
    const int w    = tid >> 6;
    const int lane = tid & 63;
    const int q  = lane >> 4;
    const int c  = lane & 15;
    const int sw = ((c >> 1) & 3) << 3;   // XOR swizzle on the m short-index (16B chunks)

    const int b  = blockIdx.x / 192;
    const int nb = (blockIdx.x % 192) * 48;      // block's 48 q-rows (all 4 waves)

    // Q B-frags: theta[n][ch], lane col n = c (per rt tile), k = q*8+j
    bf16x8 qf[3];
#pragma unroll
    for (int rt = 0; rt < 3; ++rt)
        qf[rt] = *(const bf16x8*)(theta + (b * NQ + nb + rt * 16 + c) * 32 + q * 8);

    // ones A-frag: row m=0 all-ones -> lanes with c==0 hold 1.0 in all k
    bf16x8 onef;
    {
        unsigned v = (c == 0) ? 0x3F803F80u : 0u;
        unsigned* op = (unsigned*)&onef;
        op[0] = v; op[1] = v; op[2] = v; op[3] = v;
    }

    const unsigned short* phiB = phi + (size_t)b * MM * 32;
    const unsigned short* gTB  = gT + (size_t)b * 32 * MM;
    unsigned short* myp = sh.pld[w];

    f32x4 acc[3][2];    // [rt n-tile][s2 ci-tile]: col=n, row=ci
    f32x4 lacc[3];      // D row0 (lanes q=0, reg0) = lsum per col n
#pragma unroll
    for (int rt = 0; rt < 3; ++rt) {
        lacc[rt] = (f32x4){0.f, 0.f, 0.f, 0.f};
#pragma unroll
        for (int s2 = 0; s2 < 2; ++s2) acc[rt][s2] = (f32x4){0.f, 0.f, 0.f, 0.f};
    }

    const int t0 = w * TPW;    // this wave's first 32-m tile
    bf16x8 kf[2], vf[2];

#define LOAD_KF(m0) do {                                                      \
    kf[0] = *(const bf16x8*)(phiB + ((m0) + c) * 32 + q * 8);                 \
    kf[1] = *(const bf16x8*)(phiB + ((m0) + 16 + c) * 32 + q * 8);            \
} while (0)

#define LOAD_VF(m0) do {                                                      \
    vf[0] = *(const bf16x8*)(gTB + c * MM + (m0) + q * 8);                    \
    vf[1] = *(const bf16x8*)(gTB + (16 + c) * MM + (m0) + q * 8);             \
} while (0)

// S(rt): 2 S-MFMAs + 8 exp2 + 4 cvt_pk + 2 ds_write_b64 (no lsum VALU adds)
#define S_STEP(rt) do {                                                      \
    _Pragma("unroll")                                                        \
    for (int mct = 0; mct < 2; ++mct) {                                      \
        f32x4 z = {0.f, 0.f, 0.f, 0.f};                                      \
        f32x4 s = __builtin_amdgcn_mfma_f32_16x16x32_bf16(kf[mct], qf[rt], z, 0, 0, 0); \
        uint2 hv = {pk2(__builtin_amdgcn_exp2f(s[0]), __builtin_amdgcn_exp2f(s[1])),    \
                    pk2(__builtin_amdgcn_exp2f(s[2]), __builtin_amdgcn_exp2f(s[3]))};   \
        *(uint2*)(myp + (((rt) * 16 + c) << 5) + ((mct * 16 + 4 * q) ^ sw)) = hv;       \
    }                                                                        \
} while (0)

// PV(rt): 1 ds_read_b128 + 2 acc-MFMAs + 1 lsum-MFMA (ones row)
#define PV_STEP(rt) do {                                                     \
    bf16x8 pf = *(const bf16x8*)(myp + (((rt) * 16 + c) << 5) + ((q * 8) ^ sw)); \
    acc[rt][0] = __builtin_amdgcn_mfma_f32_16x16x32_bf16(vf[0], pf, acc[rt][0], 0, 0, 0); \
    acc[rt][1] = __builtin_amdgcn_mfma_f32_16x16x32_bf16(vf[1], pf, acc[rt][1], 0, 0, 0); \
    lacc[rt]   = __builtin_amdgcn_mfma_f32_16x16x32_bf16(onef,  pf, lacc[rt],   0, 0, 0); \
} while (0)

    // ---- prologue: tile 0 S/exp/write ----
    LOAD_KF(t0 * 32);
    LOAD_VF(t0 * 32);
    S_STEP(0); S_STEP(1); S_STEP(2);

    // ---- steady state (R13/R17-proven schedule; setprio around PV) ----
    for (int mi = 1; mi < TPW; ++mi) {
        const int m0 = (t0 + mi) * 32;
        LOAD_KF(m0);                          // kf(i), consumed by S(i) below
        __builtin_amdgcn_s_setprio(1);        // favor the 9-MFMA PV cluster
        PV_STEP(0); PV_STEP(1); PV_STEP(2);   // P(i-1) x vf(i-1)
        __builtin_amdgcn_s_setprio(0);
        LOAD_VF(m0);                          // vf(i), consumed next iter
        S_STEP(0); S_STEP(1); S_STEP(2);
    }

    // ---- epilogue: PV of last tile ----
    __builtin_amdgcn_s_setprio(1);
    PV_STEP(0); PV_STEP(1); PV_STEP(2);
    __builtin_amdgcn_s_setprio(0);

#undef LOAD_KF
#undef LOAD_VF
#undef S_STEP
#undef PV_STEP

    // ---- overlay safety: all pld reads done before ep.* writes ----
    __syncthreads();

    // ---- stage per-wave partial slices ----
    // lacc D row0 lives in lanes q=0 (lane<16), reg 0
    if (lane < 16) {
        sh.ep.lred[w][lane]      = lacc[0][0];
        sh.ep.lred[w][16 + lane] = lacc[1][0];
        sh.ep.lred[w][32 + lane] = lacc[2][0];
    }
#pragma unroll
    for (int rt = 0; rt < 3; ++rt)
#pragma unroll
        for (int s2 = 0; s2 < 2; ++s2)
            *(f32x4*)&sh.ep.red[w][rt * 16 + c][s2 * 16 + 4 * q] = acc[rt][s2];

    __syncthreads();

    // ---- cross-wave sum + normalize -> yld bf16 [ci][n] ----
    if (tid < 192) {
        const int n   = tid % 48;            // 48 n
        const int cig = (tid / 48) * 8;      // 8 ci values per thread
        float ls = (sh.ep.lred[0][n] + sh.ep.lred[1][n]) +
                   (sh.ep.lred[2][n] + sh.ep.lred[3][n]);
        float inv = 1.0f / ls;
        f32x4 s0 = {0.f, 0.f, 0.f, 0.f}, s1 = {0.f, 0.f, 0.f, 0.f};
#pragma unroll
        for (int ww = 0; ww < 4; ++ww) {
            s0 += *(const f32x4*)&sh.ep.red[ww][n][cig];
            s1 += *(const f32x4*)&sh.ep.red[ww][n][cig + 4];
        }
#pragma unroll
        for (int k = 0; k < 4; ++k) {
            sh.ep.yld[cig + k][n]     = (unsigned short)(pk2(s0[k] * inv, 0.f) & 0xffff);
            sh.ep.yld[cig + 4 + k][n] = (unsigned short)(pk2(s1[k] * inv, 0.f) & 0xffff);
        }
    }
    __syncthreads();

    // ---- fused out-projection: wave w -> chn rows w*16..w*16+15 ----
    {
        bf16x8 wof;
        {
            const float* wsrc = w_out + (w * 16 + c) * 32 + q * 8;
            f32x4 w0 = *(const f32x4*)wsrc;
            f32x4 w1 = *(const f32x4*)(wsrc + 4);
            unsigned* wk = (unsigned*)&wof;
            wk[0] = pk2(w0[0], w0[1]); wk[1] = pk2(w0[2], w0[3]);
            wk[2] = pk2(w1[0], w1[1]); wk[3] = pk2(w1[2], w1[3]);
        }
#pragma unroll
        for (int nt = 0; nt < 3; ++nt) {
            bf16x8 yf;
            unsigned short* yp = (unsigned short*)&yf;
#pragma unroll
            for (int j = 0; j < 8; ++j)
                yp[j] = sh.ep.yld[q * 8 + j][nt * 16 + c];
            f32x4 z = {0.f, 0.f, 0.f, 0.f};
            f32x4 o = __builtin_amdgcn_mfma_f32_16x16x32_bf16(wof, yf, z, 0, 0, 0);
#pragma unroll
            for (int r = 0; r < 4; ++r) {
                const int chn = w * 16 + 4 * q + r;
                const size_t addr = (size_t)(b * 64 + chn) * NQ + nb + nt * 16 + c;
                out[addr] = o[r] + b_out[chn] + x[addr];
            }
        }
    }
}

extern "C" void kernel_launch(void* const* d_in, const int* in_sizes, int n_in,
                              void* d_out, int out_size, void* d_ws, size_t ws_size,
                              hipStream_t stream) {
    const float* x       = (const float*)d_in[0];
    const float* w_theta = (const float*)d_in[1];
    const float* b_theta = (const float*)d_in[2];
    const float* w_phi   = (const float*)d_in[3];
    const float* b_phi   = (const float*)d_in[4];
    const float* w_g     = (const float*)d_in[5];
    const float* b_g     = (const float*)d_in[6];
    const float* w_out   = (const float*)d_in[7];
    const float* b_out   = (const float*)d_in[8];
    float* out = (float*)d_out;

    // ws layout (bytes):
    //   theta bf16 [4][9216][32] : 2,359,296
    //   phi   bf16 [4][4608][32] : 1,179,648
    //   gT    bf16 [4][32][4608] : 1,179,648
    unsigned short* theta = (unsigned short*)d_ws;
    unsigned short* phi   = theta + 4 * NQ * 32;
    unsigned short* gT    = phi + 4 * MM * 32;

    proj_kernel<<<576, 128, 0, stream>>>(x, w_theta, b_theta, w_phi, b_phi,
                                         w_g, b_g, theta, phi, gT);
    attn_kernel<<<768, 256, 0, stream>>>(theta, phi, gT, w_out, b_out, x, out);
}